// Round 10
// baseline (224.513 us; speedup 1.0000x reference)
//
#include <hip/hip_runtime.h>
#include <hip/hip_bf16.h>

// L=4096, N=B=64. CH=8 -> CN=512 chunks (2 WG/CU on 256 CUs).
// Scan hierarchy: 512 chunks = 64 groups x 8 = 8 supers x 8 groups x 8.
// P stored ROW-MAJOR packed (hi<<16)|lo bf16 u32; V stored fp32 transposed.
// Wave tiling 16x64 (wave-exclusive A rows, no dup). State dbuf in LDS.
// THIS ROUND: the scan pyramid (L1/L2/s3) is folded into phase1 via
// LAST-ARRIVAL CONTINUATION — each block release-arrives at its group
// counter (ACQ_REL fetch_add, R8/R9-verified coherence protocol); the 8th
// arrival performs the group's L1 scan, then cascades to super counter ->
// L2 scan -> final counter -> s3. NO SPINNING (deadlock-impossible), ~584
// atomics total, and early groups' scans overlap late groups' phase1.
#define TL 4096
#define NB 64
#define CH 8
#define CN 512
#define AS 72          // LDS row stride (bf16): 144 B (odd 16B groups -> conflict-free b128)

typedef __attribute__((ext_vector_type(8))) short short8;
typedef __attribute__((ext_vector_type(4))) short short4v;
typedef __attribute__((ext_vector_type(4))) float floatx4;
typedef __attribute__((ext_vector_type(4))) unsigned int uint4v;

__device__ inline floatx4 mfma_bf16(short8 a, short8 b, floatx4 c) {
    return __builtin_amdgcn_mfma_f32_16x16x32_bf16(a, b, c, 0, 0, 0);
}
__device__ inline short bf16_rne(float x) {
    union { __hip_bfloat16 b; unsigned short s; } u;
    u.b = __float2bfloat16(x);
    return (short)u.s;
}
// fp32 -> (hi, lo) bf16 pair. x ~= hi + lo to ~2^-17 rel.
__device__ inline void split_bf16(float x, short& h, short& l) {
    h = bf16_rne(x);
    union { unsigned u; float f; } hv; hv.u = ((unsigned)(unsigned short)h) << 16;
    l = bf16_rne(x - hv.f);
}
// 8 consecutive fp32 (2 float4) -> hi/lo bf16 fragments
__device__ inline void cvt_frag(float4 a, float4 b, short8& H, short8& L) {
    float v[8] = {a.x,a.y,a.z,a.w,b.x,b.y,b.z,b.w};
#pragma unroll
    for (int r = 0; r < 8; ++r) { short hh,ll; split_bf16(v[r],hh,ll); H[r]=hh; L[r]=ll; }
}
// 8 packed u32 (2 uint4) -> hi/lo fragments
__device__ inline void unpack_frag(uint4v a, uint4v b, short8& H, short8& L) {
#pragma unroll
    for (int r = 0; r < 4; ++r) {
        H[r]   = (short)(a[r] >> 16); L[r]   = (short)(a[r] & 0xFFFFu);
        H[4+r] = (short)(b[r] >> 16); L[4+r] = (short)(b[r] & 0xFFFFu);
    }
}

// ---------------------------------------------------------------------------
// Phase 1 + scan pyramid.
// Per chunk c: S <- A[t]*S (S0=I), V <- A[t]*V + b_t (x) i_t (step 0 direct).
// Emits P32[c] = S row-major packed hi|lo, VT[c] = V^T fp32.
// Then last-arrival continuation: group L1 scan -> super L2 scan -> s3.
// gbar layout: [0..63] group counters, [64..71] super counters, [72] final.
// ---------------------------------------------------------------------------
__global__ __launch_bounds__(256, 2)
void hippo_phase1(const float* __restrict__ inp, const float* __restrict__ Ag,
                  const float* __restrict__ Bst,
                  unsigned* __restrict__ P32, float* __restrict__ VT,
                  unsigned* __restrict__ gbar)
{
    __shared__ short SBh[2][NB][AS], SBl[2][NB][AS];
    __shared__ short VBh[2][NB][AS], VBl[2][NB][AS];
    __shared__ unsigned who;

    const int tid = threadIdx.x;
    const int c = blockIdx.x, t0 = c * CH;
    const int w = tid >> 6, lane = tid & 63;
    const int quad = lane >> 4, l15 = lane & 15;
    const int arow = 16*w + l15;     // wave-exclusive A row
    const int wr0  = 16*w + 4*quad;  // acc row base

    float4 rA[2][2];
#pragma unroll
    for (int kc = 0; kc < 2; ++kc) {
        const float* p = Ag + (size_t)(t0+1)*4096 + (size_t)arow*64 + 32*kc + 8*quad;
        rA[kc][0] = *(const float4*)p;
        rA[kc][1] = *(const float4*)(p + 4);
    }
    float4 bnxt = *(const float4*)(Bst + (size_t)(t0+1)*64 + wr0);
    float inxt[4];
#pragma unroll
    for (int ni = 0; ni < 4; ++ni) inxt[ni] = inp[(size_t)(t0+1)*64 + l15 + 16*ni];

    // ---- s=0 direct: S = A[t0] (exact fp32), V = b0 (x) i0 ----
    floatx4 accS[4], accV[4];
    {
        const float* A0 = Ag + (size_t)t0 * 4096;
        float4 b0 = *(const float4*)(Bst + (size_t)t0*64 + wr0);
        float bc[4] = {b0.x,b0.y,b0.z,b0.w};
#pragma unroll
        for (int ni = 0; ni < 4; ++ni) {
            const float ii = inp[(size_t)t0*64 + l15 + 16*ni];
#pragma unroll
            for (int r = 0; r < 4; ++r) {
                accS[ni][r] = A0[(size_t)(wr0 + r)*64 + l15 + 16*ni];
                accV[ni][r] = bc[r] * ii;
            }
        }
    }
#pragma unroll
    for (int ni = 0; ni < 4; ++ni) {
        const int cc = l15 + 16*ni;
        short4v h4, l4;
#pragma unroll
        for (int r = 0; r < 4; ++r) { short hh,ll; split_bf16(accS[ni][r],hh,ll); h4[r]=hh; l4[r]=ll; }
        *(short4v*)&SBh[0][cc][wr0] = h4; *(short4v*)&SBl[0][cc][wr0] = l4;
#pragma unroll
        for (int r = 0; r < 4; ++r) { short hh,ll; split_bf16(accV[ni][r],hh,ll); h4[r]=hh; l4[r]=ll; }
        *(short4v*)&VBh[0][cc][wr0] = h4; *(short4v*)&VBl[0][cc][wr0] = l4;
    }
    __syncthreads();

    short8 aH[2], aL[2];
#pragma unroll
    for (int kc = 0; kc < 2; ++kc) cvt_frag(rA[kc][0], rA[kc][1], aH[kc], aL[kc]);

    int cur = 0;
    float4 bcur = bnxt;
    float icur[4];
#pragma unroll
    for (int ni = 0; ni < 4; ++ni) icur[ni] = inxt[ni];

    for (int s = 1; s < CH; ++s) {
        if (s + 1 < CH) {   // prefetch A/b/i for s+1
            const int t1 = t0 + s + 1;
#pragma unroll
            for (int kc = 0; kc < 2; ++kc) {
                const float* p = Ag + (size_t)t1*4096 + (size_t)arow*64 + 32*kc + 8*quad;
                rA[kc][0] = *(const float4*)p;
                rA[kc][1] = *(const float4*)(p + 4);
            }
            bnxt = *(const float4*)(Bst + (size_t)t1*64 + wr0);
#pragma unroll
            for (int ni = 0; ni < 4; ++ni) inxt[ni] = inp[(size_t)t1*64 + l15 + 16*ni];
        }
        {
            float bc[4] = {bcur.x,bcur.y,bcur.z,bcur.w};
#pragma unroll
            for (int ni = 0; ni < 4; ++ni)
#pragma unroll
            for (int r = 0; r < 4; ++r) {
                accS[ni][r] = 0.0f;
                accV[ni][r] = bc[r] * icur[ni];
            }
        }
#pragma unroll
        for (int kc = 0; kc < 2; ++kc) {
            const int ko = 32*kc + 8*quad;
#pragma unroll
            for (int ni = 0; ni < 4; ++ni) {
                const int n = l15 + 16*ni;
                short8 sH = *(const short8*)&SBh[cur][n][ko];
                short8 sL = *(const short8*)&SBl[cur][n][ko];
                short8 vH = *(const short8*)&VBh[cur][n][ko];
                short8 vL = *(const short8*)&VBl[cur][n][ko];
                accS[ni] = mfma_bf16(aH[kc], sH, accS[ni]);
                accS[ni] = mfma_bf16(aH[kc], sL, accS[ni]);
                accS[ni] = mfma_bf16(aL[kc], sH, accS[ni]);
                accV[ni] = mfma_bf16(aH[kc], vH, accV[ni]);
                accV[ni] = mfma_bf16(aH[kc], vL, accV[ni]);
                accV[ni] = mfma_bf16(aL[kc], vH, accV[ni]);
            }
        }
        if (s + 1 < CH) {
#pragma unroll
            for (int kc = 0; kc < 2; ++kc) cvt_frag(rA[kc][0], rA[kc][1], aH[kc], aL[kc]);
            const int nb = cur ^ 1;
#pragma unroll
            for (int ni = 0; ni < 4; ++ni) {
                const int cc = l15 + 16*ni;
                short4v h4, l4;
#pragma unroll
                for (int r = 0; r < 4; ++r) { short hh,ll; split_bf16(accS[ni][r],hh,ll); h4[r]=hh; l4[r]=ll; }
                *(short4v*)&SBh[nb][cc][wr0] = h4; *(short4v*)&SBl[nb][cc][wr0] = l4;
#pragma unroll
                for (int r = 0; r < 4; ++r) { short hh,ll; split_bf16(accV[ni][r],hh,ll); h4[r]=hh; l4[r]=ll; }
                *(short4v*)&VBh[nb][cc][wr0] = h4; *(short4v*)&VBl[nb][cc][wr0] = l4;
            }
            __syncthreads();
            cur ^= 1;
        }
        bcur = bnxt;
#pragma unroll
        for (int ni = 0; ni < 4; ++ni) icur[ni] = inxt[ni];
    }

    {
        unsigned* po = P32 + (size_t)c * 4096;
#pragma unroll
        for (int ni = 0; ni < 4; ++ni) {
            const int cc = l15 + 16*ni;
            *(floatx4*)(VT + (size_t)c*4096 + cc*64 + wr0) = accV[ni];
#pragma unroll
            for (int r = 0; r < 4; ++r) {
                short hh, ll; split_bf16(accS[ni][r], hh, ll);
                po[(size_t)(wr0 + r)*64 + cc] = ((unsigned)(unsigned short)hh << 16) | (unsigned)(unsigned short)ll;
            }
        }
    }

    // =============== scan pyramid: last-arrival continuation ===============
    // In-place scan of 8 elements: slot i <- inclusive prefix 0..i.
    // (reuses SB as the P double-buffer, VB as the V double-buffer)
    auto scan8 = [&](int base, int estride) {
        {   // element 0 -> buf 0 (transpose scatter for P, row copy for V)
            const unsigned* p0 = P32 + (size_t)base * 4096;
            const float*    v0 = VT  + (size_t)base * 4096;
#pragma unroll
            for (int q = 0; q < 4; ++q) {
                int f = tid + q * 256;
                int k = f & 63, m0 = (f >> 6) * 4;
                uint4v pk = *(const uint4v*)(p0 + k * 64 + m0);
#pragma unroll
                for (int r = 0; r < 4; ++r) {
                    SBh[0][m0 + r][k] = (short)(pk[r] >> 16);
                    SBl[0][m0 + r][k] = (short)(pk[r] & 0xFFFFu);
                }
            }
#pragma unroll
            for (int q = 0; q < 4; ++q) {
                int f = tid + q * 256;
                int n = f >> 4, k0 = (f & 15) * 4;
                float4 vv = *(const float4*)(v0 + n * 64 + k0);
                float va[4] = {vv.x, vv.y, vv.z, vv.w};
                short4v vh4, vl4;
#pragma unroll
                for (int r = 0; r < 4; ++r) { short hh, ll; split_bf16(va[r], hh, ll); vh4[r]=hh; vl4[r]=ll; }
                *(short4v*)&VBh[0][n][k0] = vh4; *(short4v*)&VBl[0][n][k0] = vl4;
            }
        }
        uint4v rP[2][2]; float4 pV[4];
        {
            const unsigned* pc = P32 + (size_t)(base + estride) * 4096;
            const float*    vc = VT  + (size_t)(base + estride) * 4096;
#pragma unroll
            for (int kc = 0; kc < 2; ++kc) {
                const unsigned* p = pc + (size_t)arow*64 + 32*kc + 8*quad;
                rP[kc][0] = *(const uint4v*)p;
                rP[kc][1] = *(const uint4v*)(p + 4);
            }
#pragma unroll
            for (int ni = 0; ni < 4; ++ni)
                pV[ni] = *(const float4*)(vc + (size_t)(l15 + 16*ni)*64 + wr0);
        }
        __syncthreads();

        short8 sH2[2], sL2[2];
#pragma unroll
        for (int kc = 0; kc < 2; ++kc) unpack_frag(rP[kc][0], rP[kc][1], sH2[kc], sL2[kc]);

        int cb = 0;
        for (int i = 1; i < 8; ++i) {
            const int idx = base + i * estride;
            floatx4 accP2[4], accV2[4];
#pragma unroll
            for (int ni = 0; ni < 4; ++ni) {
                accV2[ni][0] = pV[ni].x; accV2[ni][1] = pV[ni].y;
                accV2[ni][2] = pV[ni].z; accV2[ni][3] = pV[ni].w;
                accP2[ni][0]=accP2[ni][1]=accP2[ni][2]=accP2[ni][3]=0.0f;
            }
            if (i + 1 < 8) {
                const unsigned* pc = P32 + (size_t)(base + (i+1) * estride) * 4096;
                const float*    vc = VT  + (size_t)(base + (i+1) * estride) * 4096;
#pragma unroll
                for (int kc = 0; kc < 2; ++kc) {
                    const unsigned* p = pc + (size_t)arow*64 + 32*kc + 8*quad;
                    rP[kc][0] = *(const uint4v*)p;
                    rP[kc][1] = *(const uint4v*)(p + 4);
                }
#pragma unroll
                for (int ni = 0; ni < 4; ++ni)
                    pV[ni] = *(const float4*)(vc + (size_t)(l15 + 16*ni)*64 + wr0);
            }
#pragma unroll
            for (int kc = 0; kc < 2; ++kc) {
                const int ko = 32*kc + 8*quad;
#pragma unroll
                for (int ni = 0; ni < 4; ++ni) {
                    const int n = l15 + 16*ni;
                    short8 pH = *(const short8*)&SBh[cb][n][ko];
                    short8 pL = *(const short8*)&SBl[cb][n][ko];
                    short8 vH = *(const short8*)&VBh[cb][n][ko];
                    short8 vL = *(const short8*)&VBl[cb][n][ko];
                    accP2[ni] = mfma_bf16(sH2[kc], pH, accP2[ni]);
                    accP2[ni] = mfma_bf16(sH2[kc], pL, accP2[ni]);
                    accP2[ni] = mfma_bf16(sL2[kc], pH, accP2[ni]);
                    accV2[ni] = mfma_bf16(sH2[kc], vH, accV2[ni]);
                    accV2[ni] = mfma_bf16(sH2[kc], vL, accV2[ni]);
                    accV2[ni] = mfma_bf16(sL2[kc], vH, accV2[ni]);
                }
            }
            if (i + 1 < 8) {
#pragma unroll
                for (int kc = 0; kc < 2; ++kc) unpack_frag(rP[kc][0], rP[kc][1], sH2[kc], sL2[kc]);
            }
            unsigned* po = P32 + (size_t)idx * 4096;
            const int nb = cb ^ 1;
#pragma unroll
            for (int ni = 0; ni < 4; ++ni) {
                const int cc = l15 + 16*ni;
                *(floatx4*)(VT + (size_t)idx*4096 + cc*64 + wr0) = accV2[ni];
                short4v h4, l4;
#pragma unroll
                for (int r = 0; r < 4; ++r) {
                    short hh, ll; split_bf16(accP2[ni][r], hh, ll);
                    po[(size_t)(wr0+r)*64 + cc] = ((unsigned)(unsigned short)hh << 16) | (unsigned)(unsigned short)ll;
                    h4[r]=hh; l4[r]=ll;
                }
                if (i + 1 < 8) {
                    *(short4v*)&SBh[nb][cc][wr0] = h4; *(short4v*)&SBl[nb][cc][wr0] = l4;
                    short4v vh4, vl4;
#pragma unroll
                    for (int r = 0; r < 4; ++r) { short hh,ll; split_bf16(accV2[ni][r],hh,ll); vh4[r]=hh; vl4[r]=ll; }
                    *(short4v*)&VBh[nb][cc][wr0] = vh4; *(short4v*)&VBl[nb][cc][wr0] = vl4;
                }
            }
            if (i + 1 < 8) __syncthreads();
            cb ^= 1;
        }
    };

    const int g = c >> 3;
    __syncthreads();                       // drain all waves' global stores
    if (tid == 0)
        who = __hip_atomic_fetch_add(gbar + g, 1u, __ATOMIC_ACQ_REL, __HIP_MEMORY_SCOPE_AGENT);
    __syncthreads();
    if (who != 7u) return;                 // not last in group -> done

    scan8(g * 8, 1);                       // L1: in-group prefix scan

    const int sp = g >> 3;
    __syncthreads();
    if (tid == 0)
        who = __hip_atomic_fetch_add(gbar + 64 + sp, 1u, __ATOMIC_ACQ_REL, __HIP_MEMORY_SCOPE_AGENT);
    __syncthreads();
    if (who != 7u) return;                 // not last group in super -> done

    scan8(64 * sp + 7, 8);                 // L2: in-super prefix over group aggs

    __syncthreads();
    if (tid == 0)
        who = __hip_atomic_fetch_add(gbar + 72, 1u, __ATOMIC_ACQ_REL, __HIP_MEMORY_SCOPE_AGENT);
    __syncthreads();
    if (who != 7u) return;                 // not last super -> done

    // ---- s3: E_{s+1} = P[64s+63]*E_s + V[64s+63] -> dead P32 slots (E fp32)
    {
#pragma unroll
        for (int q = 0; q < 16; ++q) {
            int f = tid + q * 256; SBh[0][f >> 6][f & 63] = 0; SBl[0][f >> 6][f & 63] = 0;
        }
        uint4v rP[2][2]; float4 pV[4];
        {
            const unsigned* pc = P32 + (size_t)63 * 4096;
            const float*    vc = VT  + (size_t)63 * 4096;
#pragma unroll
            for (int kc = 0; kc < 2; ++kc) {
                const unsigned* p = pc + (size_t)arow*64 + 32*kc + 8*quad;
                rP[kc][0] = *(const uint4v*)p;
                rP[kc][1] = *(const uint4v*)(p + 4);
            }
#pragma unroll
            for (int ni = 0; ni < 4; ++ni)
                pV[ni] = *(const float4*)(vc + (size_t)(l15 + 16*ni)*64 + wr0);
        }
        __syncthreads();

        short8 eAH[2], eAL[2];
#pragma unroll
        for (int kc = 0; kc < 2; ++kc) unpack_frag(rP[kc][0], rP[kc][1], eAH[kc], eAL[kc]);

        int cb = 0;
        for (int s = 0; s < 7; ++s) {
            const int idx = 64 * s + 63;
            floatx4 acc[4];
#pragma unroll
            for (int ni = 0; ni < 4; ++ni) {
                acc[ni][0] = pV[ni].x; acc[ni][1] = pV[ni].y;
                acc[ni][2] = pV[ni].z; acc[ni][3] = pV[ni].w;
            }
            if (s + 1 < 7) {
                const int idx2 = 64 * (s + 1) + 63;
                const unsigned* pc = P32 + (size_t)idx2 * 4096;
                const float*    vc = VT  + (size_t)idx2 * 4096;
#pragma unroll
                for (int kc = 0; kc < 2; ++kc) {
                    const unsigned* p = pc + (size_t)arow*64 + 32*kc + 8*quad;
                    rP[kc][0] = *(const uint4v*)p;
                    rP[kc][1] = *(const uint4v*)(p + 4);
                }
#pragma unroll
                for (int ni = 0; ni < 4; ++ni)
                    pV[ni] = *(const float4*)(vc + (size_t)(l15 + 16*ni)*64 + wr0);
            }
#pragma unroll
            for (int kc = 0; kc < 2; ++kc) {
                const int ko = 32*kc + 8*quad;
#pragma unroll
                for (int ni = 0; ni < 4; ++ni) {
                    const int n = l15 + 16*ni;
                    short8 eH = *(const short8*)&SBh[cb][n][ko];
                    short8 eL = *(const short8*)&SBl[cb][n][ko];
                    acc[ni] = mfma_bf16(eAH[kc], eH, acc[ni]);
                    acc[ni] = mfma_bf16(eAH[kc], eL, acc[ni]);
                    acc[ni] = mfma_bf16(eAL[kc], eH, acc[ni]);
                }
            }
            if (s + 1 < 7) {
#pragma unroll
                for (int kc = 0; kc < 2; ++kc) unpack_frag(rP[kc][0], rP[kc][1], eAH[kc], eAL[kc]);
            }
            float* eo = (float*)(P32 + (size_t)idx * 4096);
            const int nb = cb ^ 1;
#pragma unroll
            for (int ni = 0; ni < 4; ++ni) {
                const int cc = l15 + 16*ni;
                *(floatx4*)(eo + cc*64 + wr0) = acc[ni];
                if (s + 1 < 7) {
                    short4v h4, l4;
#pragma unroll
                    for (int r = 0; r < 4; ++r) { short hh,ll; split_bf16(acc[ni][r],hh,ll); h4[r]=hh; l4[r]=ll; }
                    *(short4v*)&SBh[nb][cc][wr0] = h4; *(short4v*)&SBl[nb][cc][wr0] = l4;
                }
            }
            if (s + 1 < 7) __syncthreads();
            cb ^= 1;
        }
    }
}

// ---------------------------------------------------------------------------
// Phase 3: entering state = (super E) combined with stored prefixes, then
// x <- A[t] x + u_t for 8 local steps.  A/P frags per-wave from global;
// X dbuf in LDS; one barrier per step/combine.
// ---------------------------------------------------------------------------
__global__ __launch_bounds__(256, 2)
void hippo_phase3(const float* __restrict__ inp, const float* __restrict__ Ag,
                  const float* __restrict__ Bst, const unsigned* __restrict__ P32,
                  const float* __restrict__ VT, float* __restrict__ out)
{
    __shared__ short XBh[2][NB][AS], XBl[2][NB][AS];

    const int tid = threadIdx.x, c = blockIdx.x, t0 = c * CH;
    const int w = tid >> 6, lane = tid & 63, quad = lane >> 4, l15 = lane & 15;
    const int arow = 16*w + l15;
    const int wr0  = 16*w + 4*quad;
    const int sup = c >> 6, g = c >> 3, gi = g & 7, j = c & 7;

    // issue A[t0] frag loads + b/i(t0) early (hide HBM under combines)
    float4 rA[2][2];
#pragma unroll
    for (int kc = 0; kc < 2; ++kc) {
        const float* p = Ag + (size_t)t0*4096 + (size_t)arow*64 + 32*kc + 8*quad;
        rA[kc][0] = *(const float4*)p;
        rA[kc][1] = *(const float4*)(p + 4);
    }
    float4 bcur = *(const float4*)(Bst + (size_t)t0*64 + wr0);
    float icur[4];
#pragma unroll
    for (int ni = 0; ni < 4; ++ni) icur[ni] = inp[(size_t)t0*64 + l15 + 16*ni];

    // ---- entering super state -> buf 0 ----
    if (sup == 0) {
#pragma unroll
        for (int q = 0; q < 16; ++q) { int f = tid + q*256; XBh[0][f>>6][f&63] = 0; XBl[0][f>>6][f&63] = 0; }
    } else {
        const float* e = (const float*)(P32 + (size_t)(64*(sup-1) + 63) * 4096);  // E_sup [b][n]
#pragma unroll
        for (int q = 0; q < 4; ++q) {
            int f = tid + q*256; int b = f>>4, k0 = (f&15)*4;
            float4 v = *(const float4*)(e + b*64 + k0);
            float va[4] = {v.x,v.y,v.z,v.w};
            short4v h4, l4;
#pragma unroll
            for (int r=0;r<4;++r){short hh,ll;split_bf16(va[r],hh,ll);h4[r]=hh;l4[r]=ll;}
            *(short4v*)&XBh[0][b][k0] = h4; *(short4v*)&XBl[0][b][k0] = l4;
        }
    }
    __syncthreads();
    int cur = 0;

    // ---- apply stored prefixes: X <- P[idx]*X + V[idx] ----
    auto combine = [&](int idx) {
        uint4v rP[2][2];
        const unsigned* pc = P32 + (size_t)idx * 4096;
        const float*    vc = VT  + (size_t)idx * 4096;
#pragma unroll
        for (int kc = 0; kc < 2; ++kc) {
            const unsigned* p = pc + (size_t)arow*64 + 32*kc + 8*quad;
            rP[kc][0] = *(const uint4v*)p;
            rP[kc][1] = *(const uint4v*)(p + 4);
        }
        floatx4 acc[4];
#pragma unroll
        for (int ni = 0; ni < 4; ++ni) {
            float4 vv = *(const float4*)(vc + (size_t)(l15 + 16*ni)*64 + wr0);
            acc[ni][0]=vv.x; acc[ni][1]=vv.y; acc[ni][2]=vv.z; acc[ni][3]=vv.w;
        }
        short8 cH[2], cL[2];
#pragma unroll
        for (int kc = 0; kc < 2; ++kc) unpack_frag(rP[kc][0], rP[kc][1], cH[kc], cL[kc]);
#pragma unroll
        for (int kc = 0; kc < 2; ++kc) {
            const int ko = 32*kc + 8*quad;
#pragma unroll
            for (int ni = 0; ni < 4; ++ni) {
                const int n = l15 + 16*ni;
                short8 xH = *(const short8*)&XBh[cur][n][ko];
                short8 xL = *(const short8*)&XBl[cur][n][ko];
                acc[ni] = mfma_bf16(cH[kc], xH, acc[ni]);
                acc[ni] = mfma_bf16(cH[kc], xL, acc[ni]);
                acc[ni] = mfma_bf16(cL[kc], xH, acc[ni]);
            }
        }
        const int nb = cur ^ 1;
#pragma unroll
        for (int ni = 0; ni < 4; ++ni) {
            const int cc = l15 + 16*ni;
            short4v h4, l4;
#pragma unroll
            for (int r=0;r<4;++r){short hh,ll;split_bf16(acc[ni][r],hh,ll);h4[r]=hh;l4[r]=ll;}
            *(short4v*)&XBh[nb][cc][wr0] = h4; *(short4v*)&XBl[nb][cc][wr0] = l4;
        }
        __syncthreads();
        cur ^= 1;
    };
    if (gi) combine(8*g - 1);   // in-super group prefix (L2 output)
    if (j)  combine(c - 1);     // in-group chunk prefix (L1 output)

    // convert A[t0] frags (loads issued at kernel start)
    short8 aH[2], aL[2];
#pragma unroll
    for (int kc = 0; kc < 2; ++kc) cvt_frag(rA[kc][0], rA[kc][1], aH[kc], aL[kc]);

    // ---- 8 local time steps ----
    float4 bnxt; float inxt[4];
    floatx4 acc[4];
    for (int s = 0; s < CH; ++s) {
        const int t = t0 + s;
        if (s + 1 < CH) {
            const int t1 = t + 1;
#pragma unroll
            for (int kc = 0; kc < 2; ++kc) {
                const float* p = Ag + (size_t)t1*4096 + (size_t)arow*64 + 32*kc + 8*quad;
                rA[kc][0] = *(const float4*)p;
                rA[kc][1] = *(const float4*)(p + 4);
            }
            bnxt = *(const float4*)(Bst + (size_t)t1*64 + wr0);
#pragma unroll
            for (int ni = 0; ni < 4; ++ni) inxt[ni] = inp[(size_t)t1*64 + l15 + 16*ni];
        }
        {
            float bc[4] = {bcur.x,bcur.y,bcur.z,bcur.w};
#pragma unroll
            for (int ni=0;ni<4;++ni)
#pragma unroll
            for (int r=0;r<4;++r) acc[ni][r] = bc[r] * icur[ni];
        }
#pragma unroll
        for (int kc = 0; kc < 2; ++kc) {
            const int ko = 32*kc + 8*quad;
#pragma unroll
            for (int ni = 0; ni < 4; ++ni) {
                const int n = l15 + 16*ni;
                short8 xH = *(const short8*)&XBh[cur][n][ko];
                short8 xL = *(const short8*)&XBl[cur][n][ko];
                acc[ni] = mfma_bf16(aH[kc], xH, acc[ni]);
                acc[ni] = mfma_bf16(aH[kc], xL, acc[ni]);
                acc[ni] = mfma_bf16(aL[kc], xH, acc[ni]);
            }
        }
        if (s + 1 < CH) {
#pragma unroll
            for (int kc = 0; kc < 2; ++kc) cvt_frag(rA[kc][0], rA[kc][1], aH[kc], aL[kc]);
        }
        const int nb = cur ^ 1;
#pragma unroll
        for (int ni = 0; ni < 4; ++ni) {
            const int cc = l15 + 16*ni;
            *(floatx4*)(out + (size_t)t*4096 + cc*64 + wr0) = acc[ni];   // out[t][b][n0..3]
            if (s + 1 < CH) {
                short4v h4, l4;
#pragma unroll
                for (int r=0;r<4;++r){short hh,ll;split_bf16(acc[ni][r],hh,ll);h4[r]=hh;l4[r]=ll;}
                *(short4v*)&XBh[nb][cc][wr0] = h4; *(short4v*)&XBl[nb][cc][wr0] = l4;
            }
        }
        if (s + 1 < CH) { __syncthreads(); cur ^= 1; }
        bcur = bnxt;
#pragma unroll
        for (int ni = 0; ni < 4; ++ni) icur[ni] = inxt[ni];
    }
}

extern "C" void kernel_launch(void* const* d_in, const int* in_sizes, int n_in,
                              void* d_out, int out_size, void* d_ws, size_t ws_size,
                              hipStream_t stream)
{
    const float* inp = (const float*)d_in[0];   // (L, B)
    const float* A   = (const float*)d_in[1];   // (L, N, N)
    const float* Bst = (const float*)d_in[2];   // (L, N)
    float* out = (float*)d_out;                  // (L, B, N)
    float* ws  = (float*)d_ws;

    unsigned* P32 = (unsigned*)ws;                   // 8 MB: packed hi|lo, row-major
    float*    VT  = (float*)ws + (size_t)CN * 4096;  // 8 MB: fp32, transposed
    unsigned* gbar = (unsigned*)((char*)d_ws + (size_t)16 * 1024 * 1024);  // 73 counters

    hipMemsetAsync(gbar, 0, 128 * sizeof(unsigned), stream);
    hippo_phase1<<<CN, 256, 0, stream>>>(inp, A, Bst, P32, VT, gbar);
    hippo_phase3<<<CN, 256, 0, stream>>>(inp, A, Bst, P32, VT, out);
}